// Round 10
// baseline (182.481 us; speedup 1.0000x reference)
//
#include <hip/hip_runtime.h>
#include <math.h>

#define BATCH_N 16384

typedef _Float16 half8 __attribute__((ext_vector_type(8)));
typedef __fp16 h2 __attribute__((ext_vector_type(2)));   // cvt_pkrtz / fdot2 type
typedef float f32x4 __attribute__((ext_vector_type(4)));

// ---------------------------------------------------------------------------
// LDS float-index map (7688 floats = 30752 B -> 5 blocks/CU):
//  [0,120)     C1P   conv1 w as f16 pairs [oc][ky][4]: (w0,w1),(w2,w3),(w4,0),(0,w4)
//  [120,126)   BS1   conv1 bias
//  [128,144)   BS2   conv2 bias
//  [144,628)   FC2W  fc2 w (480) + b (4)
//  [628,724)   ROTM  12 gates x 8 (batch-uniform Rot matrices)
//  [724,788)   RXCS  rx cos[32] + sin[32]
//  [788,838)   CWB   clf w (40) + b (10)
//  [840,2696)  W2B   conv2 w f16 [16 oc][232], k' = tap*8+ic
//  [2696,7688) PW    per-wave scratch, 1248 floats (2496 halves) each:
//     during conv1/conv2: H1C f16 [2 s][156 units][8]  (unit = py*13+px)
//     conv2 epilogue:     H2(s) overlays own PW at (s&1)*256 halves [H1C dead]
//     fc1 phase:          HS f16 [8 s][128] overlays wave0 PW at +512 halves
// ---------------------------------------------------------------------------
#define C1P_F  0
#define BS1_F  120
#define BS2_F  128
#define FC2W_F 144
#define ROTM_F 628
#define RXCS_F 724
#define CWB_F  788
#define W2B_F  840
#define PW_F   2696
#define LDS_FLOATS 7688

__global__ __launch_bounds__(256, 5) void fused_model(
    const float* __restrict__ xg,
    const float* __restrict__ c1w, const float* __restrict__ c1b,
    const float* __restrict__ c2w, const float* __restrict__ c2b,
    const float* __restrict__ f1w, const float* __restrict__ f1b,
    const float* __restrict__ f2w, const float* __restrict__ f2b,
    const float* __restrict__ qw,  const float* __restrict__ cw,
    const float* __restrict__ cbias, float* __restrict__ out) {
    __shared__ float L[LDS_FLOATS];
    const int tid = threadIdx.x;
    const int b0 = blockIdx.x * 8;
    const int lane = tid & 63, wvi = tid >> 6;
    const int ml = lane & 15, q = lane >> 4;

    _Float16* W2BH = (_Float16*)(L + W2B_F);
    _Float16* PWH  = (_Float16*)(L + PW_F);
    _Float16* H1CH = PWH + wvi * 2496;
    _Float16* HSH  = PWH + 512;   // wave0 region, units 64..192 (dead there)

    // ================= stage shared constants (one barrier) ================
    if (tid < 120) {  // conv1 weight f16 pairs
        const int oc = tid / 20, r = tid - oc * 20, ky = r >> 2, j = r & 3;
        const float* wb = c1w + oc * 25 + ky * 5;
        float lo, hi;
        if (j == 0)      { lo = wb[0]; hi = wb[1]; }
        else if (j == 1) { lo = wb[2]; hi = wb[3]; }
        else if (j == 2) { lo = wb[4]; hi = 0.f;   }
        else             { lo = 0.f;   hi = wb[4]; }
        ((h2*)&L[C1P_F])[tid] = __builtin_amdgcn_cvt_pkrtz(lo, hi);
    }
    if (tid < 6)  L[BS1_F + tid] = c1b[tid];
    if (tid < 16) L[BS2_F + tid] = c2b[tid];
    for (int i = tid; i < 480; i += 256) L[FC2W_F + i] = f2w[i];
    if (tid < 4) L[FC2W_F + 480 + tid] = f2b[tid];
    if (tid < 40) L[CWB_F + tid] = cw[tid];
    if (tid < 10) L[CWB_F + 40 + tid] = cbias[tid];
    if (tid < 12) {  // Rot gate matrices (batch-uniform)
        const float phi = qw[tid * 3 + 0];
        const float th  = qw[tid * 3 + 1];
        const float om  = qw[tid * 3 + 2];
        const float ct = cosf(0.5f * th), st = sinf(0.5f * th);
        const float ap = 0.5f * (phi + om), bm = 0.5f * (phi - om);
        const float ca = cosf(ap), sa = sinf(ap);
        const float cbm = cosf(bm), sbm = sinf(bm);
        float* R = &L[ROTM_F + tid * 8];
        R[0] =  ct * ca;  R[1] = -ct * sa;
        R[2] = -st * cbm; R[3] = -st * sbm;
        R[4] =  st * cbm; R[5] = -st * sbm;
        R[6] =  ct * ca;  R[7] =  ct * sa;
    }
    for (int i = tid; i < 3712; i += 256) {
        const int oc = i / 232, r = i - oc * 232;
        float v = 0.f;
        if (r < 200) {
            const int pix = r >> 3, ic = r & 7;
            if (ic < 6) v = c2w[oc * 150 + ic * 25 + pix];
        }
        W2BH[oc * 232 + r] = (_Float16)v;
    }
    __syncthreads();

    // ============ per-wave conv1 (dot2 f16, fp32 acc) -> H1C ===============
    for (int t = lane; t < 288; t += 64) {
        const int s = t >= 144 ? 1 : 0;
        const int r = t - s * 144;
        const int py = r / 12, px = r - (r / 12) * 12;
        const float* xp = xg + (size_t)(b0 + 2 * wvi + s) * 784 + (2 * py) * 28 + 2 * px;

        // 6x6 patch as f16 pairs: A = aligned (c0c1,c2c3,c4c5), S = shifted (c1c2,c3c4)
        h2 A[6][3], S[6][2];
#pragma unroll
        for (int rr = 0; rr < 6; rr++) {
            const float2 a = *(const float2*)(xp + rr * 28);
            const float2 b = *(const float2*)(xp + rr * 28 + 2);
            const float2 c = *(const float2*)(xp + rr * 28 + 4);
            A[rr][0] = __builtin_amdgcn_cvt_pkrtz(a.x, a.y);
            A[rr][1] = __builtin_amdgcn_cvt_pkrtz(b.x, b.y);
            A[rr][2] = __builtin_amdgcn_cvt_pkrtz(c.x, c.y);
            S[rr][0] = __builtin_amdgcn_cvt_pkrtz(a.y, b.x);
            S[rr][1] = __builtin_amdgcn_cvt_pkrtz(b.y, c.x);
        }

        union { _Float16 h[8]; uint4 u; } O;
#pragma unroll
        for (int oc = 0; oc < 6; oc++) {
            union { uint4 v; h2 h[4]; } W[5];
#pragma unroll
            for (int ky = 0; ky < 5; ky++)
                W[ky].v = ((const uint4*)&L[C1P_F])[oc * 5 + ky];
            const float bv = L[BS1_F + oc];
            float a00 = bv, a01 = bv, a10 = bv, a11 = bv;
#pragma unroll
            for (int ky = 0; ky < 5; ky++) {
                a00 = __builtin_amdgcn_fdot2(A[ky][0],     W[ky].h[0], a00, false);
                a00 = __builtin_amdgcn_fdot2(A[ky][1],     W[ky].h[1], a00, false);
                a00 = __builtin_amdgcn_fdot2(A[ky][2],     W[ky].h[2], a00, false);
                a01 = __builtin_amdgcn_fdot2(S[ky][0],     W[ky].h[0], a01, false);
                a01 = __builtin_amdgcn_fdot2(S[ky][1],     W[ky].h[1], a01, false);
                a01 = __builtin_amdgcn_fdot2(A[ky][2],     W[ky].h[3], a01, false);
                a10 = __builtin_amdgcn_fdot2(A[ky + 1][0], W[ky].h[0], a10, false);
                a10 = __builtin_amdgcn_fdot2(A[ky + 1][1], W[ky].h[1], a10, false);
                a10 = __builtin_amdgcn_fdot2(A[ky + 1][2], W[ky].h[2], a10, false);
                a11 = __builtin_amdgcn_fdot2(S[ky + 1][0], W[ky].h[0], a11, false);
                a11 = __builtin_amdgcn_fdot2(S[ky + 1][1], W[ky].h[1], a11, false);
                a11 = __builtin_amdgcn_fdot2(A[ky + 1][2], W[ky].h[3], a11, false);
            }
            const float m = fmaxf(fmaxf(a00, a01), fmaxf(a10, a11));
            O.h[oc] = (_Float16)fmaxf(m, 0.f);
        }
        O.h[6] = (_Float16)0.f; O.h[7] = (_Float16)0.f;
        *(uint4*)(H1CH + s * 1248 + (py * 13 + px) * 8) = O.u;
    }
    __builtin_amdgcn_wave_barrier();

    // ============ per-wave conv2 via MFMA (b128 fragments) =================
    {
        f32x4 c2a[2][4];
#pragma unroll
        for (int a = 0; a < 2; a++)
#pragma unroll
            for (int b = 0; b < 4; b++) c2a[a][b] = (f32x4){0.f, 0.f, 0.f, 0.f};

#pragma unroll
        for (int ks = 0; ks < 7; ks++) {
            const half8 bfrag = *(const half8*)(W2BH + ml * 232 + ks * 32 + q * 8);
            int tp = ks * 4 + q; if (tp > 24) tp = 24;  // pad taps: B=0
            const int poff = (tp / 5) * 13 + (tp % 5);
#pragma unroll
            for (int si = 0; si < 2; si++) {
                const _Float16* hp = H1CH + si * 1248;
#pragma unroll
                for (int t = 0; t < 4; t++) {
                    const int cp = t * 16 + ml;
                    const int unit = (cp >> 3) * 13 + (cp & 7) + poff;
                    const half8 afrag = *(const half8*)(hp + unit * 8);
                    c2a[si][t] = __builtin_amdgcn_mfma_f32_16x16x32_f16(afrag, bfrag, c2a[si][t], 0, 0, 0);
                }
            }
        }

        // bias + pool + relu -> H2 overlays own PW (H1C dead now)
        const float bv = L[BS2_F + ml];
#pragma unroll
        for (int si = 0; si < 2; si++) {
#pragma unroll
            for (int t = 0; t < 4; t++) {
                const float c0 = c2a[si][t][0] + bv, c1 = c2a[si][t][1] + bv;
                const float c2 = c2a[si][t][2] + bv, c3 = c2a[si][t][3] + bv;
                float px0 = fmaxf(c0, c1), px1 = fmaxf(c2, c3);
                px0 = fmaxf(px0, __shfl_xor(px0, 32));
                px1 = fmaxf(px1, __shfl_xor(px1, 32));
                if (lane < 32) {
                    union { _Float16 h[2]; unsigned u; } P2;
                    P2.h[0] = (_Float16)fmaxf(px0, 0.f);
                    P2.h[1] = (_Float16)fmaxf(px1, 0.f);
                    *(unsigned*)(PWH + wvi * 2496 + si * 256 + ml * 16 + t * 4 + (q & 1) * 2) = P2.u;
                }
            }
        }
    }
    __syncthreads();

    // ============ fc1 (256->120) via MFMA, M=8 samples =====================
    {
        f32x4 fcC[2];
        fcC[0] = (f32x4){0.f, 0.f, 0.f, 0.f};
        fcC[1] = (f32x4){0.f, 0.f, 0.f, 0.f};
        const int ms = (ml < 8) ? ml : 0;
        const _Float16* h2p = PWH + (ms >> 1) * 2496 + (ms & 1) * 256;
#pragma unroll
        for (int ks = 0; ks < 8; ks++) {
            const half8 afrag = *(const half8*)(h2p + ks * 32 + q * 8);
#pragma unroll
            for (int ti = 0; ti < 2; ti++) {
                const int n = (wvi + 4 * ti) * 16 + ml;
                half8 bfrag;
                if (n < 120) {
                    const float* wp = f1w + (size_t)n * 256 + ks * 32 + q * 8;
                    const float4 u = *(const float4*)wp;
                    const float4 v = *(const float4*)(wp + 4);
                    bfrag[0] = (_Float16)u.x; bfrag[1] = (_Float16)u.y;
                    bfrag[2] = (_Float16)u.z; bfrag[3] = (_Float16)u.w;
                    bfrag[4] = (_Float16)v.x; bfrag[5] = (_Float16)v.y;
                    bfrag[6] = (_Float16)v.z; bfrag[7] = (_Float16)v.w;
                } else {
#pragma unroll
                    for (int j = 0; j < 8; j++) bfrag[j] = (_Float16)0.f;
                }
                fcC[ti] = __builtin_amdgcn_mfma_f32_16x16x32_f16(afrag, bfrag, fcC[ti], 0, 0, 0);
            }
        }
        if (q < 2) {
#pragma unroll
            for (int ti = 0; ti < 2; ti++) {
                const int n = (wvi + 4 * ti) * 16 + ml;
                if (n < 120) {
                    const float bb = f1b[n];
#pragma unroll
                    for (int rg = 0; rg < 4; rg++) {
                        const int s = q * 4 + rg;
                        HSH[s * 128 + n] = (_Float16)fmaxf(fcC[ti][rg] + bb, 0.f);
                    }
                }
            }
        }
    }
    __syncthreads();

    // ============ fc2 (120->4) + pi*sigmoid -> rx cos/sin ==================
    if (tid < 32) {
        const int s = tid >> 2, m = tid & 3;
        float f = L[FC2W_F + 480 + m];
        for (int nn = 0; nn < 120; nn += 8) {
            const half8 hv = *(const half8*)(HSH + s * 128 + nn);
            const float* wp = &L[FC2W_F + m * 120 + nn];
            f = fmaf(wp[0], (float)hv[0], f); f = fmaf(wp[1], (float)hv[1], f);
            f = fmaf(wp[2], (float)hv[2], f); f = fmaf(wp[3], (float)hv[3], f);
            f = fmaf(wp[4], (float)hv[4], f); f = fmaf(wp[5], (float)hv[5], f);
            f = fmaf(wp[6], (float)hv[6], f); f = fmaf(wp[7], (float)hv[7], f);
        }
        const float ang = 3.14159265358979323846f / (1.f + expf(-f));
        L[RXCS_F + tid]      = cosf(0.5f * ang);
        L[RXCS_F + 32 + tid] = sinf(0.5f * ang);
    }
    __syncthreads();

    // ============ circuit: 8 samples x 16 amplitudes on 2 waves ============
    if (tid < 128) {
        const int s = tid >> 4, a = tid & 15;
        float ar = (a == 0) ? 1.f : 0.f, ai = 0.f;

#pragma unroll
        for (int l = 0; l < 3; l++) {
#pragma unroll
            for (int w = 0; w < 4; w++) {
                const float* R = &L[ROTM_F + (l * 4 + w) * 8];
                const int mask = 8 >> w;
                const float pr = __shfl_xor(ar, mask);
                const float pi = __shfl_xor(ai, mask);
                const bool bit = (a & mask) != 0;
                const float lr = bit ? pr : ar, li = bit ? pi : ai;
                const float hr = bit ? ar : pr, hi = bit ? ai : pi;
                const float Ar = bit ? R[4] : R[0], Ai = bit ? R[5] : R[1];
                const float Br = bit ? R[6] : R[2], Bi = bit ? R[7] : R[3];
                ar = Ar * lr - Ai * li + Br * hr - Bi * hi;
                ai = Ar * li + Ai * lr + Br * hi + Bi * hr;
            }
#pragma unroll
            for (int w = 0; w < 4; w++) {
                const int mc = 8 >> w, mt = 8 >> ((w + 1) & 3);
                const float pr = __shfl_xor(ar, mt);
                const float pi = __shfl_xor(ai, mt);
                const bool ctrl = (a & mc) != 0;
                ar = ctrl ? pr : ar;
                ai = ctrl ? pi : ai;
            }
#pragma unroll
            for (int w = 0; w < 4; w++) {
                const int mask = 8 >> w;
                const float c  = L[RXCS_F + s * 4 + w];
                const float s2 = L[RXCS_F + 32 + s * 4 + w];
                const float pr = __shfl_xor(ar, mask);
                const float pi = __shfl_xor(ai, mask);
                const float nr = fmaf(c, ar, s2 * pi);
                const float ni = fmaf(c, ai, -s2 * pr);
                ar = nr; ai = ni;
            }
        }

        float v = ar * ar + ai * ai;
#pragma unroll
        for (int d = 1; d < 16; d <<= 1) {
            const float pv = __shfl_xor(v, d);
            v = (a & d) ? (pv - v) : (v + pv);
        }

        if (a < 10) {
            const int base = (tid & 63) & ~15;
            float lg = L[CWB_F + 40 + a];
#pragma unroll
            for (int w = 0; w < 4; w++) {
                const float zw = __shfl(v, base | (8 >> w));
                lg = fmaf(L[CWB_F + a * 4 + w], zw, lg);
            }
            out[(size_t)(b0 + s) * 10 + a] = lg;
        }
    }
}

// ---------------------------------------------------------------------------
extern "C" void kernel_launch(void* const* d_in, const int* in_sizes, int n_in,
                              void* d_out, int out_size, void* d_ws, size_t ws_size,
                              hipStream_t stream) {
    const float* x   = (const float*)d_in[0];
    const float* c1w = (const float*)d_in[1];
    const float* c1b = (const float*)d_in[2];
    const float* c2w = (const float*)d_in[3];
    const float* c2b = (const float*)d_in[4];
    const float* f1w = (const float*)d_in[5];
    const float* f1b = (const float*)d_in[6];
    const float* f2w = (const float*)d_in[7];
    const float* f2b = (const float*)d_in[8];
    const float* qw  = (const float*)d_in[9];
    const float* cw  = (const float*)d_in[10];
    const float* cb  = (const float*)d_in[11];
    float* out = (float*)d_out;

    fused_model<<<BATCH_N / 8, 256, 0, stream>>>(x, c1w, c1b, c2w, c2b,
                                                 f1w, f1b, f2w, f2b,
                                                 qw, cw, cb, out);
}

// Round 11
// 175.633 us; speedup vs baseline: 1.0390x; 1.0390x over previous
//
#include <hip/hip_runtime.h>
#include <math.h>

#define BATCH_N 16384

typedef _Float16 half8 __attribute__((ext_vector_type(8)));
typedef __fp16 h2 __attribute__((ext_vector_type(2)));   // cvt_pkrtz / fdot2 type
typedef float f32x4 __attribute__((ext_vector_type(4)));

// ---------------------------------------------------------------------------
// LDS float-index map (7688 floats = 30752 B -> 5 blocks/CU):
//  [0,120)     C1P   conv1 w as f16 pairs [oc][ky][4]: (w0,w1),(w2,w3),(w4,0),(0,w4)
//  [120,126)   BS1   conv1 bias
//  [128,144)   BS2   conv2 bias
//  [144,628)   FC2W  fc2 w (480) + b (4)
//  [628,724)   ROTM  12 gates x 8 (batch-uniform Rot matrices)
//  [724,788)   RXCS  rx cos[32] + sin[32]
//  [788,838)   CWB   clf w (40) + b (10)
//  [840,2696)  W2B   conv2 w f16 [16 oc][232], k' = tap*8+ic
//  [2696,7688) PW    per-wave scratch, 1248 floats (2496 halves) each:
//     during conv1/conv2: H1C f16 [2 s][156 units][8]  (unit = py*13+px)
//     conv2 epilogue:     H2(s) overlays own PW at (s&1)*256 halves [H1C dead]
//     fc1 phase:          HS f16 [8 s][128] overlays wave0 PW at +512 halves
// ---------------------------------------------------------------------------
#define C1P_F  0
#define BS1_F  120
#define BS2_F  128
#define FC2W_F 144
#define ROTM_F 628
#define RXCS_F 724
#define CWB_F  788
#define W2B_F  840
#define PW_F   2696
#define LDS_FLOATS 7688

__global__ __launch_bounds__(256, 5) void fused_model(
    const float* __restrict__ xg,
    const float* __restrict__ c1w, const float* __restrict__ c1b,
    const float* __restrict__ c2w, const float* __restrict__ c2b,
    const float* __restrict__ f1w, const float* __restrict__ f1b,
    const float* __restrict__ f2w, const float* __restrict__ f2b,
    const float* __restrict__ qw,  const float* __restrict__ cw,
    const float* __restrict__ cbias, float* __restrict__ out) {
    __shared__ float L[LDS_FLOATS];
    const int tid = threadIdx.x;
    const int b0 = blockIdx.x * 8;
    const int lane = tid & 63, wvi = tid >> 6;
    const int ml = lane & 15, q = lane >> 4;

    _Float16* W2BH = (_Float16*)(L + W2B_F);
    _Float16* PWH  = (_Float16*)(L + PW_F);
    _Float16* H1CH = PWH + wvi * 2496;
    _Float16* HSH  = PWH + 512;   // wave0 region, units 64..192 (dead there)

    // ================= stage shared constants (one barrier) ================
    if (tid < 120) {  // conv1 weight f16 pairs
        const int oc = tid / 20, r = tid - oc * 20, ky = r >> 2, j = r & 3;
        const float* wb = c1w + oc * 25 + ky * 5;
        float lo, hi;
        if (j == 0)      { lo = wb[0]; hi = wb[1]; }
        else if (j == 1) { lo = wb[2]; hi = wb[3]; }
        else if (j == 2) { lo = wb[4]; hi = 0.f;   }
        else             { lo = 0.f;   hi = wb[4]; }
        ((h2*)&L[C1P_F])[tid] = __builtin_amdgcn_cvt_pkrtz(lo, hi);
    }
    if (tid < 6)  L[BS1_F + tid] = c1b[tid];
    if (tid < 16) L[BS2_F + tid] = c2b[tid];
    for (int i = tid; i < 480; i += 256) L[FC2W_F + i] = f2w[i];
    if (tid < 4) L[FC2W_F + 480 + tid] = f2b[tid];
    if (tid < 40) L[CWB_F + tid] = cw[tid];
    if (tid < 10) L[CWB_F + 40 + tid] = cbias[tid];
    if (tid < 12) {  // Rot gate matrices (batch-uniform)
        const float phi = qw[tid * 3 + 0];
        const float th  = qw[tid * 3 + 1];
        const float om  = qw[tid * 3 + 2];
        const float ct = cosf(0.5f * th), st = sinf(0.5f * th);
        const float ap = 0.5f * (phi + om), bm = 0.5f * (phi - om);
        const float ca = cosf(ap), sa = sinf(ap);
        const float cbm = cosf(bm), sbm = sinf(bm);
        float* R = &L[ROTM_F + tid * 8];
        R[0] =  ct * ca;  R[1] = -ct * sa;
        R[2] = -st * cbm; R[3] = -st * sbm;
        R[4] =  st * cbm; R[5] = -st * sbm;
        R[6] =  ct * ca;  R[7] =  ct * sa;
    }
    for (int i = tid; i < 3712; i += 256) {
        const int oc = i / 232, r = i - oc * 232;
        float v = 0.f;
        if (r < 200) {
            const int pix = r >> 3, ic = r & 7;
            if (ic < 6) v = c2w[oc * 150 + ic * 25 + pix];
        }
        W2BH[oc * 232 + r] = (_Float16)v;
    }
    __syncthreads();

    // ============ per-wave conv1 (dot2 f16, row-streaming) -> H1C ==========
    // Row r of the 6x6 patch is live only during ky=r-1 and ky=r: 2 rows
    // (10 regs) + 24 accs stay under the VGPR cap -> no scratch spills.
    for (int t = lane; t < 288; t += 64) {
        const int s = t >= 144 ? 1 : 0;
        const int r = t - s * 144;
        const int py = r / 12, px = r - (r / 12) * 12;
        const float* xp = xg + (size_t)(b0 + 2 * wvi + s) * 784 + (2 * py) * 28 + 2 * px;

        float acc[6][4];
#pragma unroll
        for (int oc = 0; oc < 6; oc++) {
            const float bv = L[BS1_F + oc];
            acc[oc][0] = bv; acc[oc][1] = bv; acc[oc][2] = bv; acc[oc][3] = bv;
        }

        h2 R0[5], R1[5];  // [A0,A1,A2,S0,S1] for current / next row
        {
            const float2 a = *(const float2*)(xp);
            const float2 b = *(const float2*)(xp + 2);
            const float2 c = *(const float2*)(xp + 4);
            R0[0] = __builtin_amdgcn_cvt_pkrtz(a.x, a.y);
            R0[1] = __builtin_amdgcn_cvt_pkrtz(b.x, b.y);
            R0[2] = __builtin_amdgcn_cvt_pkrtz(c.x, c.y);
            R0[3] = __builtin_amdgcn_cvt_pkrtz(a.y, b.x);
            R0[4] = __builtin_amdgcn_cvt_pkrtz(b.y, c.x);
        }
#pragma unroll
        for (int ky = 0; ky < 5; ky++) {
            {
                const float* rp = xp + (ky + 1) * 28;
                const float2 a = *(const float2*)(rp);
                const float2 b = *(const float2*)(rp + 2);
                const float2 c = *(const float2*)(rp + 4);
                R1[0] = __builtin_amdgcn_cvt_pkrtz(a.x, a.y);
                R1[1] = __builtin_amdgcn_cvt_pkrtz(b.x, b.y);
                R1[2] = __builtin_amdgcn_cvt_pkrtz(c.x, c.y);
                R1[3] = __builtin_amdgcn_cvt_pkrtz(a.y, b.x);
                R1[4] = __builtin_amdgcn_cvt_pkrtz(b.y, c.x);
            }
#pragma unroll
            for (int oc = 0; oc < 6; oc++) {
                union { uint4 v; h2 h[4]; } W;
                W.v = ((const uint4*)&L[C1P_F])[oc * 5 + ky];
                acc[oc][0] = __builtin_amdgcn_fdot2(R0[0], W.h[0], acc[oc][0], false);
                acc[oc][0] = __builtin_amdgcn_fdot2(R0[1], W.h[1], acc[oc][0], false);
                acc[oc][0] = __builtin_amdgcn_fdot2(R0[2], W.h[2], acc[oc][0], false);
                acc[oc][1] = __builtin_amdgcn_fdot2(R0[3], W.h[0], acc[oc][1], false);
                acc[oc][1] = __builtin_amdgcn_fdot2(R0[4], W.h[1], acc[oc][1], false);
                acc[oc][1] = __builtin_amdgcn_fdot2(R0[2], W.h[3], acc[oc][1], false);
                acc[oc][2] = __builtin_amdgcn_fdot2(R1[0], W.h[0], acc[oc][2], false);
                acc[oc][2] = __builtin_amdgcn_fdot2(R1[1], W.h[1], acc[oc][2], false);
                acc[oc][2] = __builtin_amdgcn_fdot2(R1[2], W.h[2], acc[oc][2], false);
                acc[oc][3] = __builtin_amdgcn_fdot2(R1[3], W.h[0], acc[oc][3], false);
                acc[oc][3] = __builtin_amdgcn_fdot2(R1[4], W.h[1], acc[oc][3], false);
                acc[oc][3] = __builtin_amdgcn_fdot2(R1[2], W.h[3], acc[oc][3], false);
            }
#pragma unroll
            for (int j = 0; j < 5; j++) R0[j] = R1[j];
        }

        union { _Float16 h[8]; uint4 u; } O;
#pragma unroll
        for (int oc = 0; oc < 6; oc++) {
            const float m = fmaxf(fmaxf(acc[oc][0], acc[oc][1]), fmaxf(acc[oc][2], acc[oc][3]));
            O.h[oc] = (_Float16)fmaxf(m, 0.f);
        }
        O.h[6] = (_Float16)0.f; O.h[7] = (_Float16)0.f;
        *(uint4*)(H1CH + s * 1248 + (py * 13 + px) * 8) = O.u;
    }
    __builtin_amdgcn_wave_barrier();

    // ============ per-wave conv2 via MFMA (b128 fragments) =================
    {
        f32x4 c2a[2][4];
#pragma unroll
        for (int a = 0; a < 2; a++)
#pragma unroll
            for (int b = 0; b < 4; b++) c2a[a][b] = (f32x4){0.f, 0.f, 0.f, 0.f};

#pragma unroll
        for (int ks = 0; ks < 7; ks++) {
            const half8 bfrag = *(const half8*)(W2BH + ml * 232 + ks * 32 + q * 8);
            int tp = ks * 4 + q; if (tp > 24) tp = 24;  // pad taps: B=0
            const int poff = (tp / 5) * 13 + (tp % 5);
#pragma unroll
            for (int si = 0; si < 2; si++) {
                const _Float16* hp = H1CH + si * 1248;
#pragma unroll
                for (int t = 0; t < 4; t++) {
                    const int cp = t * 16 + ml;
                    const int unit = (cp >> 3) * 13 + (cp & 7) + poff;
                    const half8 afrag = *(const half8*)(hp + unit * 8);
                    c2a[si][t] = __builtin_amdgcn_mfma_f32_16x16x32_f16(afrag, bfrag, c2a[si][t], 0, 0, 0);
                }
            }
        }

        // bias + pool + relu -> H2 overlays own PW (H1C dead now)
        const float bv = L[BS2_F + ml];
#pragma unroll
        for (int si = 0; si < 2; si++) {
#pragma unroll
            for (int t = 0; t < 4; t++) {
                const float c0 = c2a[si][t][0] + bv, c1 = c2a[si][t][1] + bv;
                const float c2 = c2a[si][t][2] + bv, c3 = c2a[si][t][3] + bv;
                float px0 = fmaxf(c0, c1), px1 = fmaxf(c2, c3);
                px0 = fmaxf(px0, __shfl_xor(px0, 32));
                px1 = fmaxf(px1, __shfl_xor(px1, 32));
                if (lane < 32) {
                    union { _Float16 h[2]; unsigned u; } P2;
                    P2.h[0] = (_Float16)fmaxf(px0, 0.f);
                    P2.h[1] = (_Float16)fmaxf(px1, 0.f);
                    *(unsigned*)(PWH + wvi * 2496 + si * 256 + ml * 16 + t * 4 + (q & 1) * 2) = P2.u;
                }
            }
        }
    }
    __syncthreads();

    // ============ fc1 (256->120) via MFMA, M=8 samples =====================
    {
        f32x4 fcC[2];
        fcC[0] = (f32x4){0.f, 0.f, 0.f, 0.f};
        fcC[1] = (f32x4){0.f, 0.f, 0.f, 0.f};
        const int ms = (ml < 8) ? ml : 0;
        const _Float16* h2p = PWH + (ms >> 1) * 2496 + (ms & 1) * 256;
#pragma unroll
        for (int ks = 0; ks < 8; ks++) {
            const half8 afrag = *(const half8*)(h2p + ks * 32 + q * 8);
#pragma unroll
            for (int ti = 0; ti < 2; ti++) {
                const int n = (wvi + 4 * ti) * 16 + ml;
                half8 bfrag;
                if (n < 120) {
                    const float* wp = f1w + (size_t)n * 256 + ks * 32 + q * 8;
                    const float4 u = *(const float4*)wp;
                    const float4 v = *(const float4*)(wp + 4);
                    bfrag[0] = (_Float16)u.x; bfrag[1] = (_Float16)u.y;
                    bfrag[2] = (_Float16)u.z; bfrag[3] = (_Float16)u.w;
                    bfrag[4] = (_Float16)v.x; bfrag[5] = (_Float16)v.y;
                    bfrag[6] = (_Float16)v.z; bfrag[7] = (_Float16)v.w;
                } else {
#pragma unroll
                    for (int j = 0; j < 8; j++) bfrag[j] = (_Float16)0.f;
                }
                fcC[ti] = __builtin_amdgcn_mfma_f32_16x16x32_f16(afrag, bfrag, fcC[ti], 0, 0, 0);
            }
        }
        if (q < 2) {
#pragma unroll
            for (int ti = 0; ti < 2; ti++) {
                const int n = (wvi + 4 * ti) * 16 + ml;
                if (n < 120) {
                    const float bb = f1b[n];
#pragma unroll
                    for (int rg = 0; rg < 4; rg++) {
                        const int s = q * 4 + rg;
                        HSH[s * 128 + n] = (_Float16)fmaxf(fcC[ti][rg] + bb, 0.f);
                    }
                }
            }
        }
    }
    __syncthreads();

    // ============ fc2 (120->4) + pi*sigmoid -> rx cos/sin ==================
    if (tid < 32) {
        const int s = tid >> 2, m = tid & 3;
        float f = L[FC2W_F + 480 + m];
        for (int nn = 0; nn < 120; nn += 8) {
            const half8 hv = *(const half8*)(HSH + s * 128 + nn);
            const float* wp = &L[FC2W_F + m * 120 + nn];
            f = fmaf(wp[0], (float)hv[0], f); f = fmaf(wp[1], (float)hv[1], f);
            f = fmaf(wp[2], (float)hv[2], f); f = fmaf(wp[3], (float)hv[3], f);
            f = fmaf(wp[4], (float)hv[4], f); f = fmaf(wp[5], (float)hv[5], f);
            f = fmaf(wp[6], (float)hv[6], f); f = fmaf(wp[7], (float)hv[7], f);
        }
        const float ang = 3.14159265358979323846f / (1.f + expf(-f));
        L[RXCS_F + tid]      = cosf(0.5f * ang);
        L[RXCS_F + 32 + tid] = sinf(0.5f * ang);
    }
    __syncthreads();

    // ============ circuit: 8 samples x 16 amplitudes on 2 waves ============
    if (tid < 128) {
        const int s = tid >> 4, a = tid & 15;
        float ar = (a == 0) ? 1.f : 0.f, ai = 0.f;

#pragma unroll
        for (int l = 0; l < 3; l++) {
#pragma unroll
            for (int w = 0; w < 4; w++) {
                const float* R = &L[ROTM_F + (l * 4 + w) * 8];
                const int mask = 8 >> w;
                const float pr = __shfl_xor(ar, mask);
                const float pi = __shfl_xor(ai, mask);
                const bool bit = (a & mask) != 0;
                const float lr = bit ? pr : ar, li = bit ? pi : ai;
                const float hr = bit ? ar : pr, hi = bit ? ai : pi;
                const float Ar = bit ? R[4] : R[0], Ai = bit ? R[5] : R[1];
                const float Br = bit ? R[6] : R[2], Bi = bit ? R[7] : R[3];
                ar = Ar * lr - Ai * li + Br * hr - Bi * hi;
                ai = Ar * li + Ai * lr + Br * hi + Bi * hr;
            }
#pragma unroll
            for (int w = 0; w < 4; w++) {
                const int mc = 8 >> w, mt = 8 >> ((w + 1) & 3);
                const float pr = __shfl_xor(ar, mt);
                const float pi = __shfl_xor(ai, mt);
                const bool ctrl = (a & mc) != 0;
                ar = ctrl ? pr : ar;
                ai = ctrl ? pi : ai;
            }
#pragma unroll
            for (int w = 0; w < 4; w++) {
                const int mask = 8 >> w;
                const float c  = L[RXCS_F + s * 4 + w];
                const float s2 = L[RXCS_F + 32 + s * 4 + w];
                const float pr = __shfl_xor(ar, mask);
                const float pi = __shfl_xor(ai, mask);
                const float nr = fmaf(c, ar, s2 * pi);
                const float ni = fmaf(c, ai, -s2 * pr);
                ar = nr; ai = ni;
            }
        }

        float v = ar * ar + ai * ai;
#pragma unroll
        for (int d = 1; d < 16; d <<= 1) {
            const float pv = __shfl_xor(v, d);
            v = (a & d) ? (pv - v) : (v + pv);
        }

        if (a < 10) {
            const int base = (tid & 63) & ~15;
            float lg = L[CWB_F + 40 + a];
#pragma unroll
            for (int w = 0; w < 4; w++) {
                const float zw = __shfl(v, base | (8 >> w));
                lg = fmaf(L[CWB_F + a * 4 + w], zw, lg);
            }
            out[(size_t)(b0 + s) * 10 + a] = lg;
        }
    }
}

// ---------------------------------------------------------------------------
extern "C" void kernel_launch(void* const* d_in, const int* in_sizes, int n_in,
                              void* d_out, int out_size, void* d_ws, size_t ws_size,
                              hipStream_t stream) {
    const float* x   = (const float*)d_in[0];
    const float* c1w = (const float*)d_in[1];
    const float* c1b = (const float*)d_in[2];
    const float* c2w = (const float*)d_in[3];
    const float* c2b = (const float*)d_in[4];
    const float* f1w = (const float*)d_in[5];
    const float* f1b = (const float*)d_in[6];
    const float* f2w = (const float*)d_in[7];
    const float* f2b = (const float*)d_in[8];
    const float* qw  = (const float*)d_in[9];
    const float* cw  = (const float*)d_in[10];
    const float* cb  = (const float*)d_in[11];
    float* out = (float*)d_out;

    fused_model<<<BATCH_N / 8, 256, 0, stream>>>(x, c1w, c1b, c2w, c2b,
                                                 f1w, f1b, f2w, f2b,
                                                 qw, cw, cb, out);
}

// Round 12
// 161.740 us; speedup vs baseline: 1.1282x; 1.0859x over previous
//
#include <hip/hip_runtime.h>
#include <math.h>

#define BATCH_N 16384

typedef _Float16 half8 __attribute__((ext_vector_type(8)));
typedef __fp16 h2 __attribute__((ext_vector_type(2)));   // cvt_pkrtz / fdot2 type
typedef float f32x4 __attribute__((ext_vector_type(4)));

// ---------------------------------------------------------------------------
// LDS float-index map (7688 floats = 30752 B -> 5 blocks/CU):
//  [0,120)     C1P   conv1 w as f16 pairs [oc][ky][4]: (w0,w1),(w2,w3),(w4,0),(0,w4)
//  [120,126)   BS1   conv1 bias
//  [128,144)   BS2   conv2 bias
//  [144,628)   FC2W  fc2 w (480) + b (4)
//  [628,724)   ROTM  12 gates x 8 (batch-uniform Rot matrices)
//  [724,788)   RXCS  rx cos[32] + sin[32]
//  [788,838)   CWB   clf w (40) + b (10)
//  [840,2696)  W2B   conv2 w f16 [16 oc][232], k' = tap*8+ic
//  [2696,7688) PW    per-wave scratch, 1248 floats (2496 halves) each:
//     during conv1/conv2: H1C f16 [2 s][156 units][8]  (unit = py*13+px)
//     conv2 epilogue:     H2(s) overlays own PW at (s&1)*256 halves [H1C dead]
//     fc1 phase:          HS f16 [8 s][128] overlays wave0 PW at +512 halves
// ---------------------------------------------------------------------------
#define C1P_F  0
#define BS1_F  120
#define BS2_F  128
#define FC2W_F 144
#define ROTM_F 628
#define RXCS_F 724
#define CWB_F  788
#define W2B_F  840
#define PW_F   2696
#define LDS_FLOATS 7688

__global__ __launch_bounds__(256, 5) void fused_model(
    const float* __restrict__ xg,
    const float* __restrict__ c1w, const float* __restrict__ c1b,
    const float* __restrict__ c2w, const float* __restrict__ c2b,
    const float* __restrict__ f1w, const float* __restrict__ f1b,
    const float* __restrict__ f2w, const float* __restrict__ f2b,
    const float* __restrict__ qw,  const float* __restrict__ cw,
    const float* __restrict__ cbias, float* __restrict__ out) {
    __shared__ float L[LDS_FLOATS];
    const int tid = threadIdx.x;
    const int b0 = blockIdx.x * 8;
    const int lane = tid & 63, wvi = tid >> 6;
    const int ml = lane & 15, q = lane >> 4;

    _Float16* W2BH = (_Float16*)(L + W2B_F);
    _Float16* PWH  = (_Float16*)(L + PW_F);
    _Float16* H1CH = PWH + wvi * 2496;
    _Float16* HSH  = PWH + 512;   // wave0 region, units 64..192 (dead there)

    // ================= stage shared constants (one barrier) ================
    if (tid < 120) {  // conv1 weight f16 pairs
        const int oc = tid / 20, r = tid - oc * 20, ky = r >> 2, j = r & 3;
        const float* wb = c1w + oc * 25 + ky * 5;
        float lo, hi;
        if (j == 0)      { lo = wb[0]; hi = wb[1]; }
        else if (j == 1) { lo = wb[2]; hi = wb[3]; }
        else if (j == 2) { lo = wb[4]; hi = 0.f;   }
        else             { lo = 0.f;   hi = wb[4]; }
        ((h2*)&L[C1P_F])[tid] = __builtin_amdgcn_cvt_pkrtz(lo, hi);
    }
    if (tid < 6)  L[BS1_F + tid] = c1b[tid];
    if (tid < 16) L[BS2_F + tid] = c2b[tid];
    for (int i = tid; i < 480; i += 256) L[FC2W_F + i] = f2w[i];
    if (tid < 4) L[FC2W_F + 480 + tid] = f2b[tid];
    if (tid < 40) L[CWB_F + tid] = cw[tid];
    if (tid < 10) L[CWB_F + 40 + tid] = cbias[tid];
    if (tid < 12) {  // Rot gate matrices (batch-uniform)
        const float phi = qw[tid * 3 + 0];
        const float th  = qw[tid * 3 + 1];
        const float om  = qw[tid * 3 + 2];
        const float ct = cosf(0.5f * th), st = sinf(0.5f * th);
        const float ap = 0.5f * (phi + om), bm = 0.5f * (phi - om);
        const float ca = cosf(ap), sa = sinf(ap);
        const float cbm = cosf(bm), sbm = sinf(bm);
        float* R = &L[ROTM_F + tid * 8];
        R[0] =  ct * ca;  R[1] = -ct * sa;
        R[2] = -st * cbm; R[3] = -st * sbm;
        R[4] =  st * cbm; R[5] = -st * sbm;
        R[6] =  ct * ca;  R[7] =  ct * sa;
    }
    for (int i = tid; i < 3712; i += 256) {
        const int oc = i / 232, r = i - oc * 232;
        float v = 0.f;
        if (r < 200) {
            const int pix = r >> 3, ic = r & 7;
            if (ic < 6) v = c2w[oc * 150 + ic * 25 + pix];
        }
        W2BH[oc * 232 + r] = (_Float16)v;
    }
    __syncthreads();

    // ============ per-wave conv1 (dot2 f16, batched loads) -> H1C ==========
    // All 12 row loads issued up-front into raw fp32 regs (independent, one
    // vmcnt drain) -- no serial dependent-load chain, no spill (live ~82 regs).
    for (int t = lane; t < 288; t += 64) {
        const int s = t >= 144 ? 1 : 0;
        const int r = t - s * 144;
        const int py = r / 12, px = r - (r / 12) * 12;
        const float* xp = xg + (size_t)(b0 + 2 * wvi + s) * 784 + (2 * py) * 28 + 2 * px;

        float4 X4[6]; float2 X2[6];
#pragma unroll
        for (int rr = 0; rr < 6; rr++) {
            X4[rr] = *(const float4*)(xp + rr * 28);
            X2[rr] = *(const float2*)(xp + rr * 28 + 4);
        }

        float acc[6][4];
#pragma unroll
        for (int oc = 0; oc < 6; oc++) {
            const float bv = L[BS1_F + oc];
            acc[oc][0] = bv; acc[oc][1] = bv; acc[oc][2] = bv; acc[oc][3] = bv;
        }

        h2 R0[5], R1[5];  // packed pairs [A0,A1,A2,S0,S1], rows ky and ky+1 only
        R0[0] = __builtin_amdgcn_cvt_pkrtz(X4[0].x, X4[0].y);
        R0[1] = __builtin_amdgcn_cvt_pkrtz(X4[0].z, X4[0].w);
        R0[2] = __builtin_amdgcn_cvt_pkrtz(X2[0].x, X2[0].y);
        R0[3] = __builtin_amdgcn_cvt_pkrtz(X4[0].y, X4[0].z);
        R0[4] = __builtin_amdgcn_cvt_pkrtz(X4[0].w, X2[0].x);
#pragma unroll
        for (int ky = 0; ky < 5; ky++) {
            R1[0] = __builtin_amdgcn_cvt_pkrtz(X4[ky + 1].x, X4[ky + 1].y);
            R1[1] = __builtin_amdgcn_cvt_pkrtz(X4[ky + 1].z, X4[ky + 1].w);
            R1[2] = __builtin_amdgcn_cvt_pkrtz(X2[ky + 1].x, X2[ky + 1].y);
            R1[3] = __builtin_amdgcn_cvt_pkrtz(X4[ky + 1].y, X4[ky + 1].z);
            R1[4] = __builtin_amdgcn_cvt_pkrtz(X4[ky + 1].w, X2[ky + 1].x);
#pragma unroll
            for (int oc = 0; oc < 6; oc++) {
                union { uint4 v; h2 h[4]; } W;
                W.v = ((const uint4*)&L[C1P_F])[oc * 5 + ky];
                acc[oc][0] = __builtin_amdgcn_fdot2(R0[0], W.h[0], acc[oc][0], false);
                acc[oc][0] = __builtin_amdgcn_fdot2(R0[1], W.h[1], acc[oc][0], false);
                acc[oc][0] = __builtin_amdgcn_fdot2(R0[2], W.h[2], acc[oc][0], false);
                acc[oc][1] = __builtin_amdgcn_fdot2(R0[3], W.h[0], acc[oc][1], false);
                acc[oc][1] = __builtin_amdgcn_fdot2(R0[4], W.h[1], acc[oc][1], false);
                acc[oc][1] = __builtin_amdgcn_fdot2(R0[2], W.h[3], acc[oc][1], false);
                acc[oc][2] = __builtin_amdgcn_fdot2(R1[0], W.h[0], acc[oc][2], false);
                acc[oc][2] = __builtin_amdgcn_fdot2(R1[1], W.h[1], acc[oc][2], false);
                acc[oc][2] = __builtin_amdgcn_fdot2(R1[2], W.h[2], acc[oc][2], false);
                acc[oc][3] = __builtin_amdgcn_fdot2(R1[3], W.h[0], acc[oc][3], false);
                acc[oc][3] = __builtin_amdgcn_fdot2(R1[4], W.h[1], acc[oc][3], false);
                acc[oc][3] = __builtin_amdgcn_fdot2(R1[2], W.h[3], acc[oc][3], false);
            }
#pragma unroll
            for (int j = 0; j < 5; j++) R0[j] = R1[j];
        }

        union { _Float16 h[8]; uint4 u; } O;
#pragma unroll
        for (int oc = 0; oc < 6; oc++) {
            const float m = fmaxf(fmaxf(acc[oc][0], acc[oc][1]), fmaxf(acc[oc][2], acc[oc][3]));
            O.h[oc] = (_Float16)fmaxf(m, 0.f);
        }
        O.h[6] = (_Float16)0.f; O.h[7] = (_Float16)0.f;
        *(uint4*)(H1CH + s * 1248 + (py * 13 + px) * 8) = O.u;
    }
    __builtin_amdgcn_wave_barrier();

    // ============ per-wave conv2 via MFMA (b128 fragments) =================
    {
        f32x4 c2a[2][4];
#pragma unroll
        for (int a = 0; a < 2; a++)
#pragma unroll
            for (int b = 0; b < 4; b++) c2a[a][b] = (f32x4){0.f, 0.f, 0.f, 0.f};

#pragma unroll
        for (int ks = 0; ks < 7; ks++) {
            const half8 bfrag = *(const half8*)(W2BH + ml * 232 + ks * 32 + q * 8);
            int tp = ks * 4 + q; if (tp > 24) tp = 24;  // pad taps: B=0
            const int poff = (tp / 5) * 13 + (tp % 5);
#pragma unroll
            for (int si = 0; si < 2; si++) {
                const _Float16* hp = H1CH + si * 1248;
#pragma unroll
                for (int t = 0; t < 4; t++) {
                    const int cp = t * 16 + ml;
                    const int unit = (cp >> 3) * 13 + (cp & 7) + poff;
                    const half8 afrag = *(const half8*)(hp + unit * 8);
                    c2a[si][t] = __builtin_amdgcn_mfma_f32_16x16x32_f16(afrag, bfrag, c2a[si][t], 0, 0, 0);
                }
            }
        }

        // bias + pool + relu -> H2 overlays own PW (H1C dead now)
        const float bv = L[BS2_F + ml];
#pragma unroll
        for (int si = 0; si < 2; si++) {
#pragma unroll
            for (int t = 0; t < 4; t++) {
                const float c0 = c2a[si][t][0] + bv, c1 = c2a[si][t][1] + bv;
                const float c2 = c2a[si][t][2] + bv, c3 = c2a[si][t][3] + bv;
                float px0 = fmaxf(c0, c1), px1 = fmaxf(c2, c3);
                px0 = fmaxf(px0, __shfl_xor(px0, 32));
                px1 = fmaxf(px1, __shfl_xor(px1, 32));
                if (lane < 32) {
                    union { _Float16 h[2]; unsigned u; } P2;
                    P2.h[0] = (_Float16)fmaxf(px0, 0.f);
                    P2.h[1] = (_Float16)fmaxf(px1, 0.f);
                    *(unsigned*)(PWH + wvi * 2496 + si * 256 + ml * 16 + t * 4 + (q & 1) * 2) = P2.u;
                }
            }
        }
    }
    __syncthreads();

    // ============ fc1 (256->120) via MFMA, M=8 samples =====================
    {
        f32x4 fcC[2];
        fcC[0] = (f32x4){0.f, 0.f, 0.f, 0.f};
        fcC[1] = (f32x4){0.f, 0.f, 0.f, 0.f};
        const int ms = (ml < 8) ? ml : 0;
        const _Float16* h2p = PWH + (ms >> 1) * 2496 + (ms & 1) * 256;
#pragma unroll
        for (int ks = 0; ks < 8; ks++) {
            const half8 afrag = *(const half8*)(h2p + ks * 32 + q * 8);
#pragma unroll
            for (int ti = 0; ti < 2; ti++) {
                const int n = (wvi + 4 * ti) * 16 + ml;
                half8 bfrag;
                if (n < 120) {
                    const float* wp = f1w + (size_t)n * 256 + ks * 32 + q * 8;
                    const float4 u = *(const float4*)wp;
                    const float4 v = *(const float4*)(wp + 4);
                    bfrag[0] = (_Float16)u.x; bfrag[1] = (_Float16)u.y;
                    bfrag[2] = (_Float16)u.z; bfrag[3] = (_Float16)u.w;
                    bfrag[4] = (_Float16)v.x; bfrag[5] = (_Float16)v.y;
                    bfrag[6] = (_Float16)v.z; bfrag[7] = (_Float16)v.w;
                } else {
#pragma unroll
                    for (int j = 0; j < 8; j++) bfrag[j] = (_Float16)0.f;
                }
                fcC[ti] = __builtin_amdgcn_mfma_f32_16x16x32_f16(afrag, bfrag, fcC[ti], 0, 0, 0);
            }
        }
        if (q < 2) {
#pragma unroll
            for (int ti = 0; ti < 2; ti++) {
                const int n = (wvi + 4 * ti) * 16 + ml;
                if (n < 120) {
                    const float bb = f1b[n];
#pragma unroll
                    for (int rg = 0; rg < 4; rg++) {
                        const int s = q * 4 + rg;
                        HSH[s * 128 + n] = (_Float16)fmaxf(fcC[ti][rg] + bb, 0.f);
                    }
                }
            }
        }
    }
    __syncthreads();

    // ============ fc2 (120->4) + pi*sigmoid -> rx cos/sin ==================
    if (tid < 32) {
        const int s = tid >> 2, m = tid & 3;
        float f = L[FC2W_F + 480 + m];
        for (int nn = 0; nn < 120; nn += 8) {
            const half8 hv = *(const half8*)(HSH + s * 128 + nn);
            const float* wp = &L[FC2W_F + m * 120 + nn];
            f = fmaf(wp[0], (float)hv[0], f); f = fmaf(wp[1], (float)hv[1], f);
            f = fmaf(wp[2], (float)hv[2], f); f = fmaf(wp[3], (float)hv[3], f);
            f = fmaf(wp[4], (float)hv[4], f); f = fmaf(wp[5], (float)hv[5], f);
            f = fmaf(wp[6], (float)hv[6], f); f = fmaf(wp[7], (float)hv[7], f);
        }
        const float ang = 3.14159265358979323846f / (1.f + expf(-f));
        L[RXCS_F + tid]      = cosf(0.5f * ang);
        L[RXCS_F + 32 + tid] = sinf(0.5f * ang);
    }
    __syncthreads();

    // ============ circuit: 8 samples x 16 amplitudes on 2 waves ============
    if (tid < 128) {
        const int s = tid >> 4, a = tid & 15;
        float ar = (a == 0) ? 1.f : 0.f, ai = 0.f;

#pragma unroll
        for (int l = 0; l < 3; l++) {
#pragma unroll
            for (int w = 0; w < 4; w++) {
                const float* R = &L[ROTM_F + (l * 4 + w) * 8];
                const int mask = 8 >> w;
                const float pr = __shfl_xor(ar, mask);
                const float pi = __shfl_xor(ai, mask);
                const bool bit = (a & mask) != 0;
                const float lr = bit ? pr : ar, li = bit ? pi : ai;
                const float hr = bit ? ar : pr, hi = bit ? ai : pi;
                const float Ar = bit ? R[4] : R[0], Ai = bit ? R[5] : R[1];
                const float Br = bit ? R[6] : R[2], Bi = bit ? R[7] : R[3];
                ar = Ar * lr - Ai * li + Br * hr - Bi * hi;
                ai = Ar * li + Ai * lr + Br * hi + Bi * hr;
            }
#pragma unroll
            for (int w = 0; w < 4; w++) {
                const int mc = 8 >> w, mt = 8 >> ((w + 1) & 3);
                const float pr = __shfl_xor(ar, mt);
                const float pi = __shfl_xor(ai, mt);
                const bool ctrl = (a & mc) != 0;
                ar = ctrl ? pr : ar;
                ai = ctrl ? pi : ai;
            }
#pragma unroll
            for (int w = 0; w < 4; w++) {
                const int mask = 8 >> w;
                const float c  = L[RXCS_F + s * 4 + w];
                const float s2 = L[RXCS_F + 32 + s * 4 + w];
                const float pr = __shfl_xor(ar, mask);
                const float pi = __shfl_xor(ai, mask);
                const float nr = fmaf(c, ar, s2 * pi);
                const float ni = fmaf(c, ai, -s2 * pr);
                ar = nr; ai = ni;
            }
        }

        float v = ar * ar + ai * ai;
#pragma unroll
        for (int d = 1; d < 16; d <<= 1) {
            const float pv = __shfl_xor(v, d);
            v = (a & d) ? (pv - v) : (v + pv);
        }

        if (a < 10) {
            const int base = (tid & 63) & ~15;
            float lg = L[CWB_F + 40 + a];
#pragma unroll
            for (int w = 0; w < 4; w++) {
                const float zw = __shfl(v, base | (8 >> w));
                lg = fmaf(L[CWB_F + a * 4 + w], zw, lg);
            }
            out[(size_t)(b0 + s) * 10 + a] = lg;
        }
    }
}

// ---------------------------------------------------------------------------
extern "C" void kernel_launch(void* const* d_in, const int* in_sizes, int n_in,
                              void* d_out, int out_size, void* d_ws, size_t ws_size,
                              hipStream_t stream) {
    const float* x   = (const float*)d_in[0];
    const float* c1w = (const float*)d_in[1];
    const float* c1b = (const float*)d_in[2];
    const float* c2w = (const float*)d_in[3];
    const float* c2b = (const float*)d_in[4];
    const float* f1w = (const float*)d_in[5];
    const float* f1b = (const float*)d_in[6];
    const float* f2w = (const float*)d_in[7];
    const float* f2b = (const float*)d_in[8];
    const float* qw  = (const float*)d_in[9];
    const float* cw  = (const float*)d_in[10];
    const float* cb  = (const float*)d_in[11];
    float* out = (float*)d_out;

    fused_model<<<BATCH_N / 8, 256, 0, stream>>>(x, c1w, c1b, c2w, c2b,
                                                 f1w, f1b, f2w, f2b,
                                                 qw, cw, cb, out);
}